// Round 10
// baseline (204.666 us; speedup 1.0000x reference)
//
#include <hip/hip_runtime.h>
#include <hip/hip_bf16.h>
#include <stdint.h>

#define N_LGN   17400
#define N_POST  50000
#define NNZ     800000
#define N_BASIS 5
#define ELL_CAP 48

#define NBKT      196        // row buckets of 256 rows (50000/256 -> 196) for binning
#define NBKT_H    391        // half-buckets of 128 rows for k_build ((50000+127)/128)
#define CAPB      5120       // per-bucket edge capacity (mean 4082, +16 sigma)
#define BIN_CHUNK 4096
#define BIN_BLOCKS ((NNZ + BIN_CHUNK - 1) / BIN_CHUNK)          // 196

#define TPOSE_CBLK   32
#define TPOSE_BLOCKS ((N_LGN + TPOSE_CBLK - 1) / TPOSE_CBLK)    // 544

#define XH_STRIDE (N_LGN * 32)      // 556800 bf16x2 entries per s-half table

// ---------------- fused prep: bin edges (blocks [0,196)) + transpose (blocks [196,740)) --
// Transpose now writes the XCD-partitioned layout xTb[h][c][32]: half h holds s in
// [64h, 64h+64) as 32 bf16x2 per column. Each 2.22MB half fits one XCD's 4MB L2.
__global__ __launch_bounds__(256) void k_prep(const float* __restrict__ inp,
                                              __hip_bfloat162* __restrict__ xTb,
                                              const int2* __restrict__ idx2,
                                              const float* __restrict__ w,
                                              const int* __restrict__ syn,
                                              int* __restrict__ bucketCnt,
                                              int2* __restrict__ bEdges) {
    __shared__ alignas(16) int2 ebuf[BIN_CHUNK];       // 32KB (transpose aliases tile here)
    __shared__ unsigned char sbuf[BIN_CHUNK];          // bucket id per buffer slot
    __shared__ int hcnt[256], hstart[256], hcur[256], gbase[256];
    int tid = threadIdx.x;
    if (blockIdx.x < BIN_BLOCKS) {
        int base = blockIdx.x * BIN_CHUNK;
        int ne = NNZ - base; if (ne > BIN_CHUNK) ne = BIN_CHUNK;
        hcnt[tid] = 0;
        __syncthreads();
        int2 pk[16]; int bk[16];
#pragma unroll
        for (int i = 0; i < 16; ++i) {
            int p = i * 256 + tid;
            bk[i] = -1;
            if (p < ne) {
                int2 rc = idx2[base + p];                  // (row, col) coalesced
                float wv = w[base + p];
                int sy = syn[base + p];
                int b  = rc.x >> 8;
                int rl = rc.x & 255;
                pk[i] = make_int2(rc.y | (sy << 15) | (rl << 19), __float_as_int(wv));
                bk[i] = b;
                atomicAdd(&hcnt[b], 1);                    // LDS histogram
            }
        }
        __syncthreads();
        int v = hcnt[tid];
        hstart[tid] = v;
        __syncthreads();
        for (int off = 1; off < 256; off <<= 1) {
            int t = (tid >= off) ? hstart[tid - off] : 0;
            __syncthreads();
            hstart[tid] += t;
            __syncthreads();
        }
        int excl = hstart[tid] - v;
        hstart[tid] = excl;
        hcur[tid]  = excl;
        if (tid < NBKT) gbase[tid] = atomicAdd(&bucketCnt[tid], v);  // one atomic per bucket
        __syncthreads();
#pragma unroll
        for (int i = 0; i < 16; ++i) {
            if (bk[i] >= 0) {
                int pos = atomicAdd(&hcur[bk[i]], 1);      // place, grouped by bucket
                ebuf[pos] = pk[i];
                sbuf[pos] = (unsigned char)bk[i];
            }
        }
        __syncthreads();
        for (int p = tid; p < ne; p += 256) {              // flush: contiguous runs per bucket
            int b  = sbuf[p];
            int gi = gbase[b] + (p - hstart[b]);
            if (gi < CAPB) bEdges[b * CAPB + gi] = ebuf[p];
        }
    } else {
        // ---- transpose x (128 x 17400) fp32 -> xTb[h][c][32] bf16x2, 32-col tiles ----
        float* tile = (float*)ebuf;                        // 32*129*4 = 16,512B <= 32KB
        int c0 = (blockIdx.x - BIN_BLOCKS) * TPOSE_CBLK;
        for (int it = 0; it < 16; ++it) {
            int flat = it * 256 + tid;
            int s  = flat >> 5;
            int cl = flat & 31;
            int c  = c0 + cl;
            float v = 0.0f;
            if (c < N_LGN) v = inp[s * N_LGN + c];
            tile[cl * 129 + s] = v;
        }
        __syncthreads();
        for (int it = 0; it < 8; ++it) {
            int flat = it * 256 + tid;
            int cl = flat >> 6;
            int sp = flat & 63;                            // s-pair index 0..63
            int c  = c0 + cl;
            if (c < N_LGN) {
                float2 f = make_float2(tile[cl * 129 + 2 * sp], tile[cl * 129 + 2 * sp + 1]);
                int hh = sp >> 5, j = sp & 31;
                xTb[hh * XH_STRIDE + c * 32 + j] = __float22bfloat162_rn(f);
            }
        }
    }
}

// ---------------- build ELL from binned edges: half-bucket blocks for occupancy ----------
__global__ __launch_bounds__(512) void k_build(const int2* __restrict__ bEdges,
                                               const int* __restrict__ bucketCnt,
                                               int2* __restrict__ ell,
                                               int* __restrict__ counts) {
    __shared__ alignas(16) int2 slab[128 * ELL_CAP];   // 49,152B: 128 rows x 48 slots
    __shared__ int rcnt[128];
    int tid   = threadIdx.x;
    int hb    = blockIdx.x;            // half-bucket id, rows [hb*128, hb*128+128)
    int B     = hb >> 1;               // source bucket in bEdges (256 rows)
    int rbase = (hb & 1) << 7;         // row-low offset within the bucket
    if (tid < 128) rcnt[tid] = 0;
    {   // zero-fill slab: ELL pad slots become exact-zero edges (col=0, w=0)
        int4* s4w = (int4*)slab;
        for (int i = tid; i < 128 * ELL_CAP / 2; i += 512) s4w[i] = make_int4(0, 0, 0, 0);
    }
    __syncthreads();
    int cnt = bucketCnt[B]; if (cnt > CAPB) cnt = CAPB;
    for (int p = tid; p < cnt; p += 512) {
        int2 e = bEdges[B * CAPB + p];                 // coalesced read
        int rl = (e.x >> 19) & 0xFF;
        int r2 = rl - rbase;
        if ((unsigned)r2 < 128u) {
            int r = atomicAdd(&rcnt[r2], 1);           // LDS atomic: cheap
            if (r < ELL_CAP)
                slab[r2 * ELL_CAP + r] =
                    make_int2((e.x & 0x7FFF) | (((e.x >> 15) & 0xF) << 16), e.y);
        }
    }
    __syncthreads();
    int row0  = hb << 7;
    int nrows = N_POST - row0; if (nrows > 128) nrows = 128;
    if (nrows <= 0) return;
    const int4* s4 = (const int4*)slab;                // slab -> global, full lines
    int4* e4 = (int4*)(ell + (size_t)row0 * ELL_CAP);
    int n4 = nrows * ELL_CAP / 2;
    for (int i = tid; i < n4; i += 512) e4[i] = s4[i];
    if (tid < nrows) counts[row0 + tid] = rcnt[tid];
}

// ---------------- CSR fallback path (used only if ws too small for ELL) ----------------
__global__ __launch_bounds__(256) void k_transpose_bf16(const float* __restrict__ inp,
                                                        __hip_bfloat162* __restrict__ xTb) {
    __shared__ float tile[64 * 129];
    int c0  = blockIdx.x * 64;
    int tid = threadIdx.x;
    for (int it = 0; it < 32; ++it) {
        int flat = it * 256 + tid;
        int s  = flat >> 6;
        int cl = flat & 63;
        int c  = c0 + cl;
        float v = 0.0f;
        if (c < N_LGN) v = inp[s * N_LGN + c];
        tile[cl * 129 + s] = v;
    }
    __syncthreads();
    for (int it = 0; it < 16; ++it) {
        int flat = it * 256 + tid;
        int cl = flat >> 6;
        int sp = flat & 63;
        int c  = c0 + cl;
        if (c < N_LGN) {
            float2 f = make_float2(tile[cl * 129 + 2 * sp], tile[cl * 129 + 2 * sp + 1]);
            xTb[c * 64 + sp] = __float22bfloat162_rn(f);
        }
    }
}

__global__ __launch_bounds__(256) void k_hist(const int4* __restrict__ idx2,
                                              int* __restrict__ counts) {
    int t = blockIdx.x * 256 + threadIdx.x;
    if (t >= NNZ / 2) return;
    int4 rc = idx2[t];
    atomicAdd(&counts[rc.x], 1);
    atomicAdd(&counts[rc.z], 1);
}

__global__ __launch_bounds__(1024) void k_scan1(const int* __restrict__ counts,
                                                int* __restrict__ rowStart,
                                                int* __restrict__ blockSums) {
    __shared__ int tmp[1024];
    int tid = threadIdx.x;
    int gid = blockIdx.x * 1024 + tid;
    int v = (gid < N_POST) ? counts[gid] : 0;
    tmp[tid] = v;
    __syncthreads();
    for (int off = 1; off < 1024; off <<= 1) {
        int t = (tid >= off) ? tmp[tid - off] : 0;
        __syncthreads();
        tmp[tid] += t;
        __syncthreads();
    }
    if (gid < N_POST) rowStart[gid] = tmp[tid] - v;
    if (tid == 1023) blockSums[blockIdx.x] = tmp[1023];
}

__global__ __launch_bounds__(64) void k_scan2(const int* __restrict__ blockSums,
                                              int* __restrict__ blockOffsets, int nblk) {
    __shared__ int tmp[64];
    int tid = threadIdx.x;
    int v = (tid < nblk) ? blockSums[tid] : 0;
    tmp[tid] = v;
    __syncthreads();
    for (int off = 1; off < 64; off <<= 1) {
        int t = (tid >= off) ? tmp[tid - off] : 0;
        __syncthreads();
        tmp[tid] += t;
        __syncthreads();
    }
    if (tid < nblk) blockOffsets[tid] = tmp[tid] - v;
}

__global__ __launch_bounds__(1024) void k_scan3(int* __restrict__ rowStart,
                                                const int* __restrict__ blockOffsets) {
    int gid = blockIdx.x * 1024 + threadIdx.x;
    if (gid < N_POST) rowStart[gid] += blockOffsets[blockIdx.x];
}

__global__ __launch_bounds__(256) void k_scatter_csr(const int4* __restrict__ idx2,
                                                     const float2* __restrict__ w2,
                                                     const int2* __restrict__ syn2,
                                                     const int* __restrict__ rowStart,
                                                     int* __restrict__ cursor,
                                                     int2* __restrict__ edges) {
    int t = blockIdx.x * 256 + threadIdx.x;
    if (t >= NNZ / 2) return;
    int4 rc = idx2[t];
    float2 ww = w2[t];
    int2 sy = syn2[t];
    int p0 = rowStart[rc.x] + atomicAdd(&cursor[rc.x], 1);
    edges[p0] = make_int2(rc.y | (sy.x << 16), __float_as_int(ww.x));
    int p1 = rowStart[rc.z] + atomicAdd(&cursor[rc.z], 1);
    edges[p1] = make_int2(rc.w | (sy.y << 16), __float_as_int(ww.y));
}

// per-edge FMA body into named accumulator arrays
#define EDGE_FMA2(P0, P1, XW, FA, F4)                                             \
    P0[0] = fmaf((XW).x, (FA).x, P0[0]); P1[0] = fmaf((XW).y, (FA).x, P1[0]);     \
    P0[1] = fmaf((XW).x, (FA).y, P0[1]); P1[1] = fmaf((XW).y, (FA).y, P1[1]);     \
    P0[2] = fmaf((XW).x, (FA).z, P0[2]); P1[2] = fmaf((XW).y, (FA).z, P1[2]);     \
    P0[3] = fmaf((XW).x, (FA).w, P0[3]); P1[3] = fmaf((XW).y, (FA).w, P1[3]);     \
    P0[4] = fmaf((XW).x, (F4),   P0[4]); P1[4] = fmaf((XW).y, (F4),   P1[4]);

// factor-read + scale + FMA for one stream (consumes already-gathered x)
#define FINISH_STREAM(P0, P1, X, EX, EY)                                          \
    {                                                                             \
        int sy_  = (EX) >> 16;                                                    \
        float w_ = __int_as_float(EY);                                            \
        float4 fA_ = *(const float4*)&facsP[sy_ * 8];                             \
        float  f4_ = facsP[sy_ * 8 + 4];                                          \
        float2 xw_ = make_float2((X).x * w_, (X).y * w_);                         \
        EDGE_FMA2(P0, P1, xw_, fA_, f4_)                                          \
    }

// ---------------- main compute (ELL): XCD-partitioned s-halves -------------------------
// Block handles 16 rows x ONE s-half (64 s). h = (blockIdx%8)>>2 pins half 0 to XCDs 0-3
// and half 1 to XCDs 4-7 (round-robin dispatch), so each XCD's gather working set is one
// 2.22MB half-table -> L2-resident, eliminating the ~44MB xTb re-fetch seen at 4.45MB.
// Per int4 edge-pair: lanes 0-31 process edge 0, lanes 32-63 edge 1 (sub=lane>>5); each
// lane gathers its s-pair (4B) -> two 128B segments per instruction. Same total FMAs as
// the full-s version (no duplication); final shfl_xor(32) folds the two lane-halves.
__global__ __launch_bounds__(512, 8) void k_compute_ell(const __hip_bfloat162* __restrict__ xTb,
                                                        const int2* __restrict__ ell,
                                                        const int* __restrict__ counts,
                                                        const float* __restrict__ sw,
                                                        float2* __restrict__ out2) {
    __shared__ alignas(16) float facsP[80];          // synaptic_weights 10x5, padded to 10x8
    __shared__ float accLds[40 * 67];                // [jj][s_half], pitch 67: 16 banks on read
    __shared__ alignas(16) int2 eLds[16 * ELL_CAP];  // 16 rows x 48 slots = 6144B
    int tid  = threadIdx.x;
    int wave = tid >> 6;
    int lane = tid & 63;
    int m    = blockIdx.x & 7;
    int h    = m >> 2;                               // s-half pinned by XCD group
    int g    = (blockIdx.x >> 3) * 4 + (m & 3);      // row-group id
    if (g >= N_POST / 16) return;                    // 782*8=6256 blocks, 3 idle
    int n0   = g * 16;

    if (tid < 50) facsP[(tid / 5) * 8 + (tid % 5)] = sw[tid];
    if (tid < 16 * ELL_CAP / 2)                      // 384 threads x int4 = 6144B coalesced
        ((int4*)eLds)[tid] = ((const int4*)(ell + (size_t)n0 * ELL_CAP))[tid];
    int cA = counts[n0 + wave];     if (cA > ELL_CAP) cA = ELL_CAP;
    int cB = counts[n0 + 8 + wave]; if (cB > ELL_CAP) cB = ELL_CAP;
    __syncthreads();

    float aA0[N_BASIS] = {0.f, 0.f, 0.f, 0.f, 0.f};
    float aA1[N_BASIS] = {0.f, 0.f, 0.f, 0.f, 0.f};
    float aB0[N_BASIS] = {0.f, 0.f, 0.f, 0.f, 0.f};
    float aB1[N_BASIS] = {0.f, 0.f, 0.f, 0.f, 0.f};

    const __hip_bfloat162* xh = xTb + h * XH_STRIDE; // this XCD-group's half-table
    const int4* epA = (const int4*)(eLds + wave * ELL_CAP);        // 2 edges per int4
    const int4* epB = (const int4*)(eLds + (wave + 8) * ELL_CAP);
    int sub = lane >> 5;                             // which edge of the pair
    int j   = lane & 31;                             // s-pair index within the half
    int mc = cA > cB ? cA : cB;                      // pad slots are exact zeros
    for (int e = 0; e < mc; e += 4) {
        int hh = e >> 1;
        int4 A0 = epA[hh], A1 = epA[hh + 1];
        int4 B0 = epB[hh], B1 = epB[hh + 1];
        int ea0 = sub ? A0.z : A0.x;  int wa0 = sub ? A0.w : A0.y;
        int ea1 = sub ? A1.z : A1.x;  int wa1 = sub ? A1.w : A1.y;
        int eb0 = sub ? B0.z : B0.x;  int wb0 = sub ? B0.w : B0.y;
        int eb1 = sub ? B1.z : B1.x;  int wb1 = sub ? B1.w : B1.y;
        // 4 independent gathers in flight (2 x 128B segments each, coalesced, L2-resident)
        float2 xA0 = __bfloat1622float2(xh[(ea0 & 0xFFFF) * 32 + j]);
        float2 xA1 = __bfloat1622float2(xh[(ea1 & 0xFFFF) * 32 + j]);
        float2 xB0 = __bfloat1622float2(xh[(eb0 & 0xFFFF) * 32 + j]);
        float2 xB1 = __bfloat1622float2(xh[(eb1 & 0xFFFF) * 32 + j]);
        FINISH_STREAM(aA0, aA1, xA0, ea0, wa0)
        FINISH_STREAM(aA0, aA1, xA1, ea1, wa1)
        FINISH_STREAM(aB0, aB1, xB0, eb0, wb0)
        FINISH_STREAM(aB0, aB1, xB1, eb1, wb1)
    }

    // fold the two lane-halves (each (row, s-pair) was accumulated by lanes j and j+32)
#pragma unroll
    for (int r = 0; r < N_BASIS; ++r) {
        aA0[r] += __shfl_xor(aA0[r], 32);
        aA1[r] += __shfl_xor(aA1[r], 32);
        aB0[r] += __shfl_xor(aB0[r], 32);
        aB1[r] += __shfl_xor(aB1[r], 32);
    }

    int base2 = g * 40;                              // 16 rows x 5 = 40 float2 per s
    int sbase = h * 64;
    // ---- phase A: rows n0..n0+7 ----
    if (lane < 32) {
#pragma unroll
        for (int r = 0; r < N_BASIS; ++r) {
            int jj = wave * 5 + r;
            accLds[jj * 67 + 2 * lane]     = aA0[r];
            accLds[jj * 67 + 2 * lane + 1] = aA1[r];
        }
    }
    __syncthreads();
    for (int it = 0; it < 3; ++it) {
        int flat = it * 512 + tid;                   // 0..1279 used: 64 s x 20 float2
        if (flat < 1280) {
            int s  = flat / 20;
            int jj = flat % 20;
            float f0 = accLds[(2 * jj) * 67 + s];
            float f1 = accLds[(2 * jj + 1) * 67 + s];
            out2[(sbase + s) * 125000 + base2 + jj] = make_float2(f0, f1);
        }
    }
    __syncthreads();                                 // WAR: all reads done before reuse
    // ---- phase B: rows n0+8..n0+15 ----
    if (lane < 32) {
#pragma unroll
        for (int r = 0; r < N_BASIS; ++r) {
            int jj = wave * 5 + r;
            accLds[jj * 67 + 2 * lane]     = aB0[r];
            accLds[jj * 67 + 2 * lane + 1] = aB1[r];
        }
    }
    __syncthreads();
    for (int it = 0; it < 3; ++it) {
        int flat = it * 512 + tid;
        if (flat < 1280) {
            int s  = flat / 20;
            int jj = flat % 20;
            float f0 = accLds[(2 * jj) * 67 + s];
            float f1 = accLds[(2 * jj + 1) * 67 + s];
            out2[(sbase + s) * 125000 + base2 + 20 + jj] = make_float2(f0, f1);
        }
    }
}

// ---------------- CSR-fallback compute: one wave per row (safety path, old layout) -------
__global__ __launch_bounds__(512, 8) void k_compute(const __hip_bfloat162* __restrict__ xTb,
                                                    const int2* __restrict__ edges,
                                                    const int* __restrict__ rowStart,
                                                    const int* __restrict__ counts,
                                                    const float* __restrict__ sw,
                                                    float2* __restrict__ out2) {
    __shared__ alignas(16) float facsP[80];
    __shared__ float accLds[40 * 133];
    int tid  = threadIdx.x;
    int wave = tid >> 6;
    int lane = tid & 63;
    int n    = blockIdx.x * 8 + wave;
    int cnt  = counts[n];

    if (tid < 50) facsP[(tid / 5) * 8 + (tid % 5)] = sw[tid];
    __syncthreads();

    float a0[N_BASIS] = {0.f, 0.f, 0.f, 0.f, 0.f};
    float a1[N_BASIS] = {0.f, 0.f, 0.f, 0.f, 0.f};

    const int2* ep = edges + rowStart[n];
    int j = 0;
    for (; j + 1 < cnt; j += 2) {
        int2 e0 = ep[j];
        int2 e1 = ep[j + 1];
        float2 x0 = __bfloat1622float2(xTb[(e0.x & 0xFFFF) * 64 + lane]);
        float2 x1 = __bfloat1622float2(xTb[(e1.x & 0xFFFF) * 64 + lane]);
        FINISH_STREAM(a0, a1, x0, e0.x, e0.y)
        FINISH_STREAM(a0, a1, x1, e1.x, e1.y)
    }
    if (j < cnt) {
        int2 e0 = ep[j];
        float2 x0 = __bfloat1622float2(xTb[(e0.x & 0xFFFF) * 64 + lane]);
        FINISH_STREAM(a0, a1, x0, e0.x, e0.y)
    }

#pragma unroll
    for (int r = 0; r < N_BASIS; ++r) {
        int jj = wave * 5 + r;
        accLds[jj * 133 + 2 * lane]     = a0[r];
        accLds[jj * 133 + 2 * lane + 1] = a1[r];
    }
    __syncthreads();

    int base2 = blockIdx.x * 20;
    for (int it = 0; it < 5; ++it) {
        int flat = it * 512 + tid;
        int s  = flat / 20;
        int jj = flat % 20;
        float f0 = accLds[(2 * jj) * 133 + s];
        float f1 = accLds[(2 * jj + 1) * 133 + s];
        out2[s * 125000 + base2 + jj] = make_float2(f0, f1);
    }
}

// ---------------- launcher ----------------
extern "C" void kernel_launch(void* const* d_in, const int* in_sizes, int n_in,
                              void* d_out, int out_size, void* d_ws, size_t ws_size,
                              hipStream_t stream) {
    const float* inp     = (const float*)d_in[0];   // (1,128,17400) fp32
    const int*   indices = (const int*)d_in[1];     // (800000,2)
    const float* weights = (const float*)d_in[2];   // (800000,)
    const float* sw      = (const float*)d_in[3];   // (10,5)
    const int*   syn     = (const int*)d_in[4];     // (800000,)

    char* ws = (char*)d_ws;
    __hip_bfloat162* xTb = (__hip_bfloat162*)(ws);          // 17400*64*4 = 4,454,400 B
    int* counts          = (int*)(ws + 4454400);            // 200,000 B

    const size_t ELL_BYTES_END = 4654400ULL + (size_t)N_POST * ELL_CAP * 8;  // 23,854,400
    bool useEll = (ws_size >= ELL_BYTES_END);

    if (useEll) {
        int2* ell = (int2*)(ws + 4654400);                  // 19,200,000 B (16B aligned)
        // d_out (128MB) doubles as scratch until k_compute_ell's epilogue overwrites it:
        int2* bEdges   = (int2*)d_out;                      // 196*5120*8 = 8,028,160 B
        int*  bucketCnt = (int*)((char*)d_out + (size_t)NBKT * CAPB * 8);  // 784 B
        hipMemsetAsync(bucketCnt, 0, 1024, stream);
        k_prep<<<BIN_BLOCKS + TPOSE_BLOCKS, 256, 0, stream>>>(
            inp, xTb, (const int2*)indices, weights, syn, bucketCnt, bEdges);
        k_build<<<NBKT_H, 512, 0, stream>>>(bEdges, bucketCnt, ell, counts);
        k_compute_ell<<<(N_POST / 16 + 3) / 4 * 8, 512, 0, stream>>>(   // 782*8 = 6256
            xTb, ell, counts, sw, (float2*)d_out);
    } else {
        int* cursor    = (int*)(ws + 4654400);              // 200,000 B (adjacent to counts)
        int* rowStart  = (int*)(ws + 4854400);              // 200,000 B
        int* blockSums = (int*)(ws + 5054400);              // 256 B
        int* blockOffs = (int*)(ws + 5054656);              // 256 B
        int2* edges    = (int2*)(ws + 5054912);             // 6,400,000 B
        hipMemsetAsync(counts, 0, 400000, stream);          // counts + cursor
        k_transpose_bf16<<<(N_LGN + 63) / 64, 256, 0, stream>>>(inp, xTb);
        k_hist<<<(NNZ / 2 + 255) / 256, 256, 0, stream>>>((const int4*)indices, counts);
        k_scan1<<<(N_POST + 1023) / 1024, 1024, 0, stream>>>(counts, rowStart, blockSums);
        k_scan2<<<1, 64, 0, stream>>>(blockSums, blockOffs, (N_POST + 1023) / 1024);
        k_scan3<<<(N_POST + 1023) / 1024, 1024, 0, stream>>>(rowStart, blockOffs);
        k_scatter_csr<<<(NNZ / 2 + 255) / 256, 256, 0, stream>>>(
            (const int4*)indices, (const float2*)weights, (const int2*)syn,
            rowStart, cursor, edges);
        k_compute<<<N_POST / 8, 512, 0, stream>>>(xTb, edges, rowStart, counts, sw,
                                                  (float2*)d_out);
    }
}